// Round 14
// baseline (78.012 us; speedup 1.0000x reference)
//
#include <hip/hip_runtime.h>
#include <hip/hip_bf16.h>

#define BB 4
#define NN 512
#define EE 256
#define HH 8
#define DD 32
#define SCALING 0.17677669529663687f  // 32^-0.5
#define PR 8   // rows per proj block
#define RL 4   // rows per fused-attn block

// ---------------------------------------------------------------------------
// Projection, one W per block (blockIdx.y: 0=Q,1=K,2=V).  Q pre-scaled
// [b,n,e]; K transposed Kt[((b*H+h)*D+d)*N+n] (coalesced reads in attn);
// V folded against Wf1/2/3 -> vw[((b*H+h)*3+c)*N+m].  768 blocks.
// ---------------------------------------------------------------------------
__global__ __launch_bounds__(256) void proj_kernel(
    const float* __restrict__ query,
    const float* __restrict__ Wq, const float* __restrict__ bq,
    const float* __restrict__ Wk, const float* __restrict__ bk,
    const float* __restrict__ Wv, const float* __restrict__ bv,
    const float* __restrict__ Wf1, const float* __restrict__ Wf2,
    const float* __restrict__ Wf3,
    float* __restrict__ Q, float* __restrict__ Kt, float* __restrict__ vw)
{
    __shared__ alignas(16) float s[PR][EE];    // 8 KB
    __shared__ alignas(16) float sv[PR][EE];   // 8 KB (V blocks only)
    const int which = blockIdx.y;
    const int row0 = blockIdx.x * PR;
    const int tid = threadIdx.x;               // output column e

    {
        const float4* src = (const float4*)(query + row0 * EE);
        ((float4*)s)[tid]       = src[tid];
        ((float4*)s)[tid + 256] = src[tid + 256];
    }
    __syncthreads();

    const float* W  = (which == 0) ? Wq : (which == 1) ? Wk : Wv;
    const float* bb = (which == 0) ? bq : (which == 1) ? bk : bv;

    float acc[PR];
    #pragma unroll
    for (int r = 0; r < PR; ++r) acc[r] = 0.f;

    const float4* W4 = (const float4*)(W + tid * EE);
    for (int j = 0; j < EE / 4; ++j) {
        const float4 w = W4[j];
        #pragma unroll
        for (int r = 0; r < PR; ++r) {
            const float4 x = *(const float4*)&s[r][4 * j];
            acc[r] += x.x * w.x + x.y * w.y + x.z * w.z + x.w * w.w;
        }
    }
    const float bbv = bb[tid];

    if (which == 0) {
        #pragma unroll
        for (int r = 0; r < PR; ++r)
            Q[(row0 + r) * EE + tid] = (acc[r] + bbv) * SCALING;
    } else if (which == 1) {
        const int h = tid >> 5, d = tid & 31;
        #pragma unroll
        for (int r = 0; r < PR; ++r) {
            const int grow = row0 + r;
            const int b = grow >> 9, n = grow & 511;
            Kt[((size_t)(b * HH + h) * DD + d) * NN + n] = acc[r] + bbv;
        }
    } else {
        #pragma unroll
        for (int r = 0; r < PR; ++r) sv[r][tid] = acc[r] + bbv;
        __syncthreads();
        if (tid < PR * 24) {                   // 192 threads: (r, h, c)
            const int r = tid / 24;
            const int rem = tid % 24;
            const int hh = rem / 3;
            const int c = rem % 3;
            const float* Wf = (c == 0) ? Wf1 : (c == 1) ? Wf2 : Wf3;
            float a = 0.f;
            #pragma unroll
            for (int dd = 0; dd < DD; ++dd)
                a += sv[r][hh * DD + dd] * Wf[hh * DD + dd];
            const int grow = row0 + r;
            const int b = grow >> 9, m = grow & 511;
            vw[((b * HH + hh) * 3 + c) * NN + m] = a;
        }
    }
}

// ---------------------------------------------------------------------------
// Fused attention tail, one (b, h, 4 rows) per block; thread = column m.
// Post-normalization: T_c(r) = sum_m e*mask*delta_c*vw_c and S(r) are block
// sums (this block sees ALL m); block adds T_c/S (+bias once, from h==0)
// into out via atomicAdd.  No P' materialization, no contract kernel, e is
// f32 end-to-end.  Grid (512, 8) = 4096 blocks.
// ---------------------------------------------------------------------------
__global__ __launch_bounds__(512) void fused_attn_kernel(
    const float* __restrict__ Q, const float* __restrict__ Kt,
    const float* __restrict__ attn_bias, const float* __restrict__ vw,
    const float* __restrict__ delta_pos,
    const int* __restrict__ drop_edge_mask, const int* __restrict__ drop_or_add,
    const float* __restrict__ bf1, const float* __restrict__ bf2,
    const float* __restrict__ bf3, float* __restrict__ out)
{
    const int bx = blockIdx.x;                 // 512 blocks in x
    const int b = bx >> 7;
    const int n0 = (bx & 127) * RL;
    const int h = blockIdx.y;
    const int m = threadIdx.x;                 // column m
    const int wv = m >> 6, ln = m & 63;

    __shared__ float red[RL][4][8];            // 512 B wave-partials

    // K column in 32 regs (coalesced loads), reused across RL rows
    const float* kp = Kt + ((size_t)(b * HH + h) * DD) * NN + m;
    float kreg[DD];
    #pragma unroll
    for (int d = 0; d < DD; ++d) kreg[d] = kp[(size_t)d * NN];

    const size_t bias_base = ((size_t)(b * HH + h) * NN + n0) * NN + m;
    const float* qb = Q + (b * NN + n0) * EE + h * DD;      // block-uniform

    const float* vwb = vw + (size_t)(b * HH + h) * 3 * NN + m;
    const float vw0 = vwb[0], vw1 = vwb[NN], vw2 = vwb[2 * NN];
    const int doa = drop_or_add[0];

    #pragma unroll
    for (int r = 0; r < RL; ++r) {
        float l = attn_bias[bias_base + (size_t)r * NN];
        #pragma unroll
        for (int d = 0; d < DD; ++d)
            l += qb[r * EE + d] * kreg[d];
        const float e = __expf(l);             // |l| ~ 10 << 88: safe

        const float mk =
            (doa != 0 && drop_edge_mask[(n0 + r) * NN + m] != 0) ? 0.f : 1.f;
        const float* dp = delta_pos + ((size_t)(b * NN + (n0 + r)) * NN + m) * 3;
        const float t = e * mk;
        float v0 = t * dp[0] * vw0;
        float v1 = t * dp[1] * vw1;
        float v2 = t * dp[2] * vw2;
        float vs = e;

        #pragma unroll
        for (int off = 32; off; off >>= 1) {
            v0 += __shfl_xor(v0, off, 64);
            v1 += __shfl_xor(v1, off, 64);
            v2 += __shfl_xor(v2, off, 64);
            vs += __shfl_xor(vs, off, 64);
        }
        if (ln == 0) {
            red[r][0][wv] = v0;
            red[r][1][wv] = v1;
            red[r][2][wv] = v2;
            red[r][3][wv] = vs;
        }
    }
    __syncthreads();

    if (m < RL) {                              // 4 threads, one per row
        const int r = m;
        float T0 = 0.f, T1 = 0.f, T2 = 0.f, S = 0.f;
        #pragma unroll
        for (int w = 0; w < 8; ++w) {
            T0 += red[r][0][w];
            T1 += red[r][1][w];
            T2 += red[r][2][w];
            S  += red[r][3][w];
        }
        const float rcpS = __builtin_amdgcn_rcpf(S);
        float* o = out + (size_t)(b * NN + n0 + r) * 3;
        const float a0 = T0 * rcpS + ((h == 0) ? bf1[0] : 0.f);
        const float a1 = T1 * rcpS + ((h == 0) ? bf2[0] : 0.f);
        const float a2 = T2 * rcpS + ((h == 0) ? bf3[0] : 0.f);
        atomicAdd(o + 0, a0);
        atomicAdd(o + 1, a1);
        atomicAdd(o + 2, a2);
    }
}

// ---------------------------------------------------------------------------
extern "C" void kernel_launch(void* const* d_in, const int* in_sizes, int n_in,
                              void* d_out, int out_size, void* d_ws, size_t ws_size,
                              hipStream_t stream)
{
    const float* query          = (const float*)d_in[0];
    const float* attn_bias      = (const float*)d_in[1];
    const float* delta_pos      = (const float*)d_in[2];
    const int*   drop_edge_mask = (const int*)d_in[3];
    const float* Wq  = (const float*)d_in[4];
    const float* bq  = (const float*)d_in[5];
    const float* Wk  = (const float*)d_in[6];
    const float* bk  = (const float*)d_in[7];
    const float* Wv  = (const float*)d_in[8];
    const float* bv  = (const float*)d_in[9];
    const float* Wf1 = (const float*)d_in[10];
    const float* bf1 = (const float*)d_in[11];
    const float* Wf2 = (const float*)d_in[12];
    const float* bf2 = (const float*)d_in[13];
    const float* Wf3 = (const float*)d_in[14];
    const float* bf3 = (const float*)d_in[15];
    const int*   drop_or_add = (const int*)d_in[16];

    float* ws = (float*)d_ws;
    float* Q   = ws;                       // 524288 floats
    float* Kt  = ws + 524288;              // 524288 floats
    float* vw  = ws + 1048576;             // 49152 floats

    // zero the 24 KB output each call: atomicAdd accumulation target
    hipMemsetAsync(d_out, 0, (size_t)out_size * sizeof(float), stream);

    proj_kernel<<<dim3(BB * NN / PR, 3), 256, 0, stream>>>(
        query, Wq, bq, Wk, bk, Wv, bv, Wf1, Wf2, Wf3, Q, Kt, vw);
    fused_attn_kernel<<<dim3(BB * NN / RL, HH), 512, 0, stream>>>(
        Q, Kt, attn_bias, vw, delta_pos, drop_edge_mask, drop_or_add,
        bf1, bf2, bf3, (float*)d_out);
}

// Round 15
// 64.447 us; speedup vs baseline: 1.2105x; 1.2105x over previous
//
#include <hip/hip_runtime.h>
#include <hip/hip_bf16.h>

#define BB 4
#define NN 512
#define EE 256
#define HH 8
#define DD 32
#define SCALING 0.17677669529663687f  // 32^-0.5
#define PR 8   // rows per proj block
#define RL 8   // rows per logits block (one head per block)

__device__ __forceinline__ float bf16lo(unsigned u) {
    return __uint_as_float(u << 16);
}
__device__ __forceinline__ float bf16hi(unsigned u) {
    return __uint_as_float(u & 0xffff0000u);
}

// ---------------------------------------------------------------------------
// Projection, one W per block (blockIdx.y: 0=Q,1=K,2=V).  Q pre-scaled
// [b,n,e]; K transposed Kt[((b*H+h)*D+d)*N+n] (coalesced reads in logits);
// V folded against Wf1/2/3 -> vw[((b*H+h)*3+c)*N+m].  768 blocks.
// ---------------------------------------------------------------------------
__global__ __launch_bounds__(256) void proj_kernel(
    const float* __restrict__ query,
    const float* __restrict__ Wq, const float* __restrict__ bq,
    const float* __restrict__ Wk, const float* __restrict__ bk,
    const float* __restrict__ Wv, const float* __restrict__ bv,
    const float* __restrict__ Wf1, const float* __restrict__ Wf2,
    const float* __restrict__ Wf3,
    float* __restrict__ Q, float* __restrict__ Kt, float* __restrict__ vw)
{
    __shared__ alignas(16) float s[PR][EE];    // 8 KB
    __shared__ alignas(16) float sv[PR][EE];   // 8 KB (V blocks only)
    const int which = blockIdx.y;
    const int row0 = blockIdx.x * PR;
    const int tid = threadIdx.x;               // output column e

    {
        const float4* src = (const float4*)(query + row0 * EE);
        ((float4*)s)[tid]       = src[tid];
        ((float4*)s)[tid + 256] = src[tid + 256];
    }
    __syncthreads();

    const float* W  = (which == 0) ? Wq : (which == 1) ? Wk : Wv;
    const float* bb = (which == 0) ? bq : (which == 1) ? bk : bv;

    float acc[PR];
    #pragma unroll
    for (int r = 0; r < PR; ++r) acc[r] = 0.f;

    const float4* W4 = (const float4*)(W + tid * EE);
    for (int j = 0; j < EE / 4; ++j) {
        const float4 w = W4[j];
        #pragma unroll
        for (int r = 0; r < PR; ++r) {
            const float4 x = *(const float4*)&s[r][4 * j];
            acc[r] += x.x * w.x + x.y * w.y + x.z * w.z + x.w * w.w;
        }
    }
    const float bbv = bb[tid];

    if (which == 0) {
        #pragma unroll
        for (int r = 0; r < PR; ++r)
            Q[(row0 + r) * EE + tid] = (acc[r] + bbv) * SCALING;
    } else if (which == 1) {
        const int h = tid >> 5, d = tid & 31;
        #pragma unroll
        for (int r = 0; r < PR; ++r) {
            const int grow = row0 + r;
            const int b = grow >> 9, n = grow & 511;
            Kt[((size_t)(b * HH + h) * DD + d) * NN + n] = acc[r] + bbv;
        }
    } else {
        #pragma unroll
        for (int r = 0; r < PR; ++r) sv[r][tid] = acc[r] + bbv;
        __syncthreads();
        if (tid < PR * 24) {                   // 192 threads: (r, h, c)
            const int r = tid / 24;
            const int rem = tid % 24;
            const int hh = rem / 3;
            const int c = rem % 3;
            const float* Wf = (c == 0) ? Wf1 : (c == 1) ? Wf2 : Wf3;
            float a = 0.f;
            #pragma unroll
            for (int dd = 0; dd < DD; ++dd)
                a += sv[r][hh * DD + dd] * Wf[hh * DD + dd];
            const int grow = row0 + r;
            const int b = grow >> 9, m = grow & 511;
            vw[((b * HH + hh) * 3 + c) * NN + m] = a;
        }
    }
}

// ---------------------------------------------------------------------------
// Logits, d-OUTER loop: K element is transient (loaded once, used for all 8
// rows, then dead) -- forces 32 K loads/thread instead of the 256 the r-outer
// form rematerialized (VGPR=32 tell).  Live state = l[8] only.  qb loads are
// block-uniform -> scalar.  No shuffles, no LDS; S recovered in contract.
// ---------------------------------------------------------------------------
__global__ __launch_bounds__(512) void logits_kernel(
    const float* __restrict__ Q, const float* __restrict__ Kt,
    const float* __restrict__ attn_bias,
    __hip_bfloat16* __restrict__ Pp)
{
    const int bx = blockIdx.x;                 // 256 blocks in x
    const int b = bx >> 6;
    const int n0 = (bx & 63) * RL;
    const int h = blockIdx.y;
    const int m = threadIdx.x;                 // column m

    const float* kp = Kt + ((size_t)(b * HH + h) * DD) * NN + m;
    const size_t bias_base = ((size_t)(b * HH + h) * NN + n0) * NN + m;
    const float* qb = Q + (b * NN + n0) * EE + h * DD;      // block-uniform

    float l[RL];
    #pragma unroll
    for (int r = 0; r < RL; ++r)
        l[r] = attn_bias[bias_base + (size_t)r * NN];

    #pragma unroll
    for (int d = 0; d < DD; ++d) {
        const float k = kp[(size_t)d * NN];    // transient: 32 loads total
        #pragma unroll
        for (int r = 0; r < RL; ++r)
            l[r] += qb[r * EE + d] * k;        // qb: scalar (uniform) loads
    }

    #pragma unroll
    for (int r = 0; r < RL; ++r) {
        const float e = __expf(l[r]);          // |l| ~ 10 << 88: safe
        Pp[((size_t)(b * HH + h) * NN + (n0 + r)) * NN + m] =
            __float2bfloat16(e);
    }
}

// ---------------------------------------------------------------------------
// Contract, wave-per-head: block = (b,n), wave w = head w, lane ln covers
// m in [8*ln, 8*ln+8).  All loads dwordx4.  S via ONE in-wave butterfly
// (from bf16 P' sums).  t_c = sum p*srcp*mask*delta_c*vw_c; 1 barrier.
// (Unchanged from R12 -- single-variable experiment on logits.)
// ---------------------------------------------------------------------------
__global__ __launch_bounds__(512) void contract_kernel(
    const __hip_bfloat16* __restrict__ Pp, const float* __restrict__ vw,
    const float* __restrict__ delta_pos,
    const int* __restrict__ drop_edge_mask, const int* __restrict__ drop_or_add,
    const float* __restrict__ bf1, const float* __restrict__ bf2,
    const float* __restrict__ bf3, float* __restrict__ out)
{
    const int blk = blockIdx.x;                // 2048 blocks
    const int b = blk >> 9, n = blk & 511;
    const int tid = threadIdx.x;
    const int w = __builtin_amdgcn_readfirstlane(tid >> 6);  // wave's head
    const int ln = tid & 63;
    const int m8 = ln * 8;

    __shared__ float r3[HH][3];

    // ---- P' (8 bf16 = one dwordx4) ----
    const uint4 pu =
        *(const uint4*)(Pp + ((size_t)(b * HH + w) * NN + n) * NN + m8);
    float p[8];
    p[0] = bf16lo(pu.x); p[1] = bf16hi(pu.x);
    p[2] = bf16lo(pu.y); p[3] = bf16hi(pu.y);
    p[4] = bf16lo(pu.z); p[5] = bf16hi(pu.z);
    p[6] = bf16lo(pu.w); p[7] = bf16hi(pu.w);

    // ---- S: in-wave butterfly over this head's full row ----
    float S = ((p[0] + p[1]) + (p[2] + p[3])) + ((p[4] + p[5]) + (p[6] + p[7]));
    #pragma unroll
    for (int off = 32; off; off >>= 1)
        S += __shfl_xor(S, off, 64);
    const float srcp = __builtin_amdgcn_rcpf(S);

    // ---- vw (3 comps x 8 m, dwordx4 pairs) ----
    const float* vwb = vw + (size_t)(b * HH + w) * 3 * NN + m8;
    const float4 va0 = *(const float4*)(vwb);
    const float4 va1 = *(const float4*)(vwb + 4);
    const float4 vb0 = *(const float4*)(vwb + NN);
    const float4 vb1 = *(const float4*)(vwb + NN + 4);
    const float4 vc0 = *(const float4*)(vwb + 2 * NN);
    const float4 vc1 = *(const float4*)(vwb + 2 * NN + 4);

    // ---- delta (24 contiguous floats = 6 dwordx4) ----
    const float* dpb = delta_pos + ((size_t)(b * NN + n) * NN + m8) * 3;
    const float4 q0 = *(const float4*)(dpb);
    const float4 q1 = *(const float4*)(dpb + 4);
    const float4 q2 = *(const float4*)(dpb + 8);
    const float4 q3 = *(const float4*)(dpb + 12);
    const float4 q4 = *(const float4*)(dpb + 16);
    const float4 q5 = *(const float4*)(dpb + 20);

    // ---- mask (8 ints = 2 dwordx4) ----
    const int4 mk0 = *(const int4*)(drop_edge_mask + n * NN + m8);
    const int4 mk1 = *(const int4*)(drop_edge_mask + n * NN + m8 + 4);
    const int doa = drop_or_add[0];

    float sc[8];
    sc[0] = (doa && mk0.x) ? 0.f : p[0] * srcp;
    sc[1] = (doa && mk0.y) ? 0.f : p[1] * srcp;
    sc[2] = (doa && mk0.z) ? 0.f : p[2] * srcp;
    sc[3] = (doa && mk0.w) ? 0.f : p[3] * srcp;
    sc[4] = (doa && mk1.x) ? 0.f : p[4] * srcp;
    sc[5] = (doa && mk1.y) ? 0.f : p[5] * srcp;
    sc[6] = (doa && mk1.z) ? 0.f : p[6] * srcp;
    sc[7] = (doa && mk1.w) ? 0.f : p[7] * srcp;

    float t0, t1, t2;
    t0  = sc[0] * q0.x * va0.x;  t1  = sc[0] * q0.y * vb0.x;  t2  = sc[0] * q0.z * vc0.x;
    t0 += sc[1] * q0.w * va0.y;  t1 += sc[1] * q1.x * vb0.y;  t2 += sc[1] * q1.y * vc0.y;
    t0 += sc[2] * q1.z * va0.z;  t1 += sc[2] * q1.w * vb0.z;  t2 += sc[2] * q2.x * vc0.z;
    t0 += sc[3] * q2.y * va0.w;  t1 += sc[3] * q2.z * vb0.w;  t2 += sc[3] * q2.w * vc0.w;
    t0 += sc[4] * q3.x * va1.x;  t1 += sc[4] * q3.y * vb1.x;  t2 += sc[4] * q3.z * vc1.x;
    t0 += sc[5] * q3.w * va1.y;  t1 += sc[5] * q4.x * vb1.y;  t2 += sc[5] * q4.y * vc1.y;
    t0 += sc[6] * q4.z * va1.z;  t1 += sc[6] * q4.w * vb1.z;  t2 += sc[6] * q5.x * vc1.z;
    t0 += sc[7] * q5.y * va1.w;  t1 += sc[7] * q5.z * vb1.w;  t2 += sc[7] * q5.w * vc1.w;

    // ---- wave butterflies, cross-head fold ----
    #pragma unroll
    for (int off = 32; off; off >>= 1) {
        t0 += __shfl_xor(t0, off, 64);
        t1 += __shfl_xor(t1, off, 64);
        t2 += __shfl_xor(t2, off, 64);
    }
    if (ln == 0) { r3[w][0] = t0; r3[w][1] = t1; r3[w][2] = t2; }
    __syncthreads();

    if (tid < 3) {
        float s = 0.f;
        #pragma unroll
        for (int hh = 0; hh < HH; ++hh) s += r3[hh][tid];
        const float bias = (tid == 0) ? bf1[0] : (tid == 1) ? bf2[0] : bf3[0];
        out[(b * NN + n) * 3 + tid] = s + bias;
    }
}

// ---------------------------------------------------------------------------
extern "C" void kernel_launch(void* const* d_in, const int* in_sizes, int n_in,
                              void* d_out, int out_size, void* d_ws, size_t ws_size,
                              hipStream_t stream)
{
    const float* query          = (const float*)d_in[0];
    const float* attn_bias      = (const float*)d_in[1];
    const float* delta_pos      = (const float*)d_in[2];
    const int*   drop_edge_mask = (const int*)d_in[3];
    const float* Wq  = (const float*)d_in[4];
    const float* bq  = (const float*)d_in[5];
    const float* Wk  = (const float*)d_in[6];
    const float* bk  = (const float*)d_in[7];
    const float* Wv  = (const float*)d_in[8];
    const float* bv  = (const float*)d_in[9];
    const float* Wf1 = (const float*)d_in[10];
    const float* bf1 = (const float*)d_in[11];
    const float* Wf2 = (const float*)d_in[12];
    const float* bf2 = (const float*)d_in[13];
    const float* Wf3 = (const float*)d_in[14];
    const float* bf3 = (const float*)d_in[15];
    const int*   drop_or_add = (const int*)d_in[16];

    float* ws = (float*)d_ws;
    float* Q   = ws;                       // 524288 floats
    float* Kt  = ws + 524288;              // 524288 floats
    float* vw  = ws + 1048576;             // 49152 floats
    __hip_bfloat16* Pp = (__hip_bfloat16*)(ws + 1228800);  // B*H*N*N bf16

    proj_kernel<<<dim3(BB * NN / PR, 3), 256, 0, stream>>>(
        query, Wq, bq, Wk, bk, Wv, bv, Wf1, Wf2, Wf3, Q, Kt, vw);
    logits_kernel<<<dim3(BB * NN / RL, HH), 512, 0, stream>>>(
        Q, Kt, attn_bias, Pp);
    contract_kernel<<<BB * NN, 512, 0, stream>>>(Pp, vw, delta_pos,
                                                 drop_edge_mask, drop_or_add,
                                                 bf1, bf2, bf3, (float*)d_out);
}